// Round 3
// baseline (894.571 us; speedup 1.0000x reference)
//
#include <hip/hip_runtime.h>

typedef unsigned int uint;
typedef unsigned short ushort;

// Problem constants
#define BB 8
#define SS 4096
#define DD 2048
#define HH 1024
#define EE 8
#define CHUNK 128
#define NCHUNK 32
#define TAU 0.7f

// GEMM tile config (round-0 proven geometry)
#define BM 128
#define BN 128
#define BK 32          // k per LDS buffer (4 groups of 8)
#define KITERS (DD / BK)   // 64

typedef short bf16x8 __attribute__((ext_vector_type(8)));    // 8 bf16 = 4 VGPRs
typedef float f32x16 __attribute__((ext_vector_type(16)));   // 32x32 C frag

// bf16 split helpers: hi = truncate-top-16(x); lo = bf16(x - hi)
__device__ inline uint pack_hi(float a, float b) {
    return (__float_as_uint(a) >> 16) | (__float_as_uint(b) & 0xFFFF0000u);
}
__device__ inline float hi_part(float a) {
    return __uint_as_float(__float_as_uint(a) & 0xFFFF0000u);
}

// ---------------------------------------------------------------------------
// Pre-pass: reorder W1 [D][H] fp32 -> W1hi/W1lo bf16 in MFMA-B-staged layout
// [D/8][H][8] (k-group major, 8 consecutive k per 16B). One thread per (kg,n).
// ---------------------------------------------------------------------------
__global__ __launch_bounds__(256) void reorder_w1_kernel(
    const float* __restrict__ W1, ushort* __restrict__ w1hi, ushort* __restrict__ w1lo)
{
    const int kg = blockIdx.x >> 2;                       // 0..255
    const int n  = ((blockIdx.x & 3) << 8) + threadIdx.x; // 0..1023
    float v[8];
#pragma unroll
    for (int j = 0; j < 8; ++j) v[j] = W1[(size_t)(kg * 8 + j) * HH + n];
    uint hi[4], lo[4];
#pragma unroll
    for (int p = 0; p < 4; ++p) {
        const float a = v[2 * p], b = v[2 * p + 1];
        hi[p] = pack_hi(a, b);
        lo[p] = pack_hi(a - hi_part(a), b - hi_part(b));
    }
    const size_t off = (size_t)kg * HH + n;               // uint4 index
    ((uint4*)w1hi)[off] = make_uint4(hi[0], hi[1], hi[2], hi[3]);
    ((uint4*)w1lo)[off] = make_uint4(lo[0], lo[1], lo[2], lo[3]);
}

// ---------------------------------------------------------------------------
// Fused router GEMM: round-0 structure + double-buffered LDS prefetch.
// One block = one (batch,chunk) x one 128-wide H slice. 3-term bf16-split
// MFMA (32x32x16). Epilogue: relu + W2 + chunk-sum -> atomicAdd.
// ---------------------------------------------------------------------------
__global__ __launch_bounds__(256, 2) void router_gemm_kernel(
    const float* __restrict__ x,
    const ushort* __restrict__ w1hi,   // [D/8][H][8] bf16 bits
    const ushort* __restrict__ w1lo,
    const float* __restrict__ b1,
    const float* __restrict__ W2,
    float* __restrict__ chunk_logits)  // [B*NCHUNK][E], pre-zeroed
{
    const int slice = blockIdx.x;      // 0..7  (H slice)
    const int bc    = blockIdx.y;      // 0..255 (batch*NCHUNK + chunk)
    const int n0    = slice * BN;

    const int tid  = threadIdx.x;      // 0..255
    const int wave = tid >> 6;         // 0..3
    const int lane = tid & 63;
    const int lm   = lane & 31;        // row/col within 32-tile
    const int kq   = lane >> 5;        // k-quadrant (0/1)
    const int wm   = (wave & 1) * 64;  // wave m offset
    const int wn   = (wave >> 1) * 64; // wave n offset

    // double-buffered tiles: [buf][kg][row][8k]
    __shared__ __align__(16) ushort As_hi[2][4][BM][8];   // 16KB
    __shared__ __align__(16) ushort As_lo[2][4][BM][8];   // 16KB
    __shared__ __align__(16) ushort Bs_hi[2][4][BN][8];   // 16KB
    __shared__ __align__(16) ushort Bs_lo[2][4][BN][8];   // 16KB
    __shared__ float  W2s[BN][EE];                         // 4KB
    __shared__ float  b1s[BN];
    __shared__ float  red[4][EE];

    const float* xrow = x + (size_t)bc * CHUNK * DD;

    // Stage W2 slice + b1 slice
    ((float4*)&W2s[0][0])[tid] = ((const float4*)(W2 + (size_t)n0 * EE))[tid];
    if (tid < BN / 4) ((float4*)b1s)[tid] = ((const float4*)(b1 + n0))[tid];

    f32x16 acc[2][2];
#pragma unroll
    for (int i = 0; i < 2; ++i)
#pragma unroll
        for (int j = 0; j < 2; ++j)
#pragma unroll
            for (int r = 0; r < 16; ++r) acc[i][j][r] = 0.0f;

    // A staging coords: thread -> (m, k-half)
    const int am = tid >> 1;          // 0..127
    const int ah = tid & 1;           // 0/1: k0+ah*16 .. +16
    const float* asrc = xrow + (size_t)am * DD + ah * 16;

// Issue B-tile async global->LDS for k-step (it) into buffer (buf).
// Identical index math to round 0, parameterized by buffer.
#define STAGE_B(it, buf) do {                                                        \
        const int kgg = (it) * 4 + wave;                                             \
        _Pragma("unroll")                                                            \
        for (int h = 0; h < 2; ++h) {                                                \
            const size_t goff = ((size_t)kgg * HH + n0 + h * 64 + lane) * 8;         \
            __builtin_amdgcn_global_load_lds(                                        \
                (const __attribute__((address_space(1))) uint*)(w1hi + goff),        \
                (__attribute__((address_space(3))) uint*)&Bs_hi[buf][wave][h * 64 + lane][0], \
                16, 0, 0);                                                           \
            __builtin_amdgcn_global_load_lds(                                        \
                (const __attribute__((address_space(1))) uint*)(w1lo + goff),        \
                (__attribute__((address_space(3))) uint*)&Bs_lo[buf][wave][h * 64 + lane][0], \
                16, 0, 0);                                                           \
        }                                                                            \
    } while (0)

// Convert 16 fp32 in v0..v3 to hi/lo bf16 and write this thread's A slots.
#define WRITE_A(v0, v1, v2, v3, buf) do {                                            \
        const float f_[16] = {v0.x, v0.y, v0.z, v0.w, v1.x, v1.y, v1.z, v1.w,        \
                              v2.x, v2.y, v2.z, v2.w, v3.x, v3.y, v3.z, v3.w};       \
        uint h_[8], l_[8];                                                           \
        _Pragma("unroll")                                                            \
        for (int p = 0; p < 8; ++p) {                                                \
            const float a_ = f_[2 * p], b_ = f_[2 * p + 1];                          \
            h_[p] = pack_hi(a_, b_);                                                 \
            l_[p] = pack_hi(a_ - hi_part(a_), b_ - hi_part(b_));                     \
        }                                                                            \
        const int kg0_ = ah * 2;                                                     \
        *(uint4*)&As_hi[buf][kg0_][am][0]     = make_uint4(h_[0], h_[1], h_[2], h_[3]); \
        *(uint4*)&As_hi[buf][kg0_ + 1][am][0] = make_uint4(h_[4], h_[5], h_[6], h_[7]); \
        *(uint4*)&As_lo[buf][kg0_][am][0]     = make_uint4(l_[0], l_[1], l_[2], l_[3]); \
        *(uint4*)&As_lo[buf][kg0_ + 1][am][0] = make_uint4(l_[4], l_[5], l_[6], l_[7]); \
    } while (0)

// MFMA phase on buffer (buf): 2 k-steps x 2x2 tiles x 3 split terms.
#define MFMA_PHASE(buf) do {                                                         \
        _Pragma("unroll")                                                            \
        for (int s = 0; s < 2; ++s) {                                                \
            const int kg = 2 * s + kq;                                               \
            bf16x8 a_h[2], a_l[2], b_h[2], b_l[2];                                   \
            _Pragma("unroll")                                                        \
            for (int i = 0; i < 2; ++i) {                                            \
                a_h[i] = *(const bf16x8*)&As_hi[buf][kg][wm + i * 32 + lm][0];       \
                a_l[i] = *(const bf16x8*)&As_lo[buf][kg][wm + i * 32 + lm][0];       \
            }                                                                        \
            _Pragma("unroll")                                                        \
            for (int j = 0; j < 2; ++j) {                                            \
                b_h[j] = *(const bf16x8*)&Bs_hi[buf][kg][wn + j * 32 + lm][0];       \
                b_l[j] = *(const bf16x8*)&Bs_lo[buf][kg][wn + j * 32 + lm][0];       \
            }                                                                        \
            _Pragma("unroll")                                                        \
            for (int i = 0; i < 2; ++i)                                              \
                _Pragma("unroll")                                                    \
                for (int j = 0; j < 2; ++j) {                                        \
                    acc[i][j] = __builtin_amdgcn_mfma_f32_32x32x16_bf16(             \
                        a_l[i], b_h[j], acc[i][j], 0, 0, 0);                         \
                    acc[i][j] = __builtin_amdgcn_mfma_f32_32x32x16_bf16(             \
                        a_h[i], b_l[j], acc[i][j], 0, 0, 0);                         \
                    acc[i][j] = __builtin_amdgcn_mfma_f32_32x32x16_bf16(             \
                        a_h[i], b_h[j], acc[i][j], 0, 0, 0);                         \
                }                                                                    \
        }                                                                            \
    } while (0)

    // ---- prologue: stage k-step 0 into buffer 0 ----
    {
        float4 v0 = ((const float4*)asrc)[0];
        float4 v1 = ((const float4*)asrc)[1];
        float4 v2 = ((const float4*)asrc)[2];
        float4 v3 = ((const float4*)asrc)[3];
        STAGE_B(0, 0);
        WRITE_A(v0, v1, v2, v3, 0);
    }
    __syncthreads();

    // ---- main loop: stage t+1 (buf^1) || compute t (buf) ----
    for (int t = 0; t < KITERS - 1; ++t) {
        const int cur = t & 1;
        // issue next-tile loads first (A->regs, B->LDS async)
        const float* s2 = asrc + (size_t)(t + 1) * BK;
        float4 v0 = ((const float4*)s2)[0];
        float4 v1 = ((const float4*)s2)[1];
        float4 v2 = ((const float4*)s2)[2];
        float4 v3 = ((const float4*)s2)[3];
        STAGE_B(t + 1, cur ^ 1);
        // compute current tile while loads fly
        MFMA_PHASE(cur);
        // convert + write next A tile
        WRITE_A(v0, v1, v2, v3, cur ^ 1);
        __syncthreads();   // single vmcnt(0)+lgkmcnt(0)+barrier per k-step
    }
    // last k-step: compute only
    MFMA_PHASE((KITERS - 1) & 1);

    // ---- Epilogue: relu + second GEMM + chunk partial sum ----
    float part[EE];
#pragma unroll
    for (int e = 0; e < EE; ++e) part[e] = 0.0f;

#pragma unroll
    for (int j = 0; j < 2; ++j) {
        const int hl = wn + j * 32 + lm;       // local h (col of C)
        const float bias = b1s[hl];
        float w2r[EE];
#pragma unroll
        for (int e = 0; e < EE; ++e) w2r[e] = W2s[hl][e];
#pragma unroll
        for (int i = 0; i < 2; ++i)
#pragma unroll
            for (int r = 0; r < 16; ++r) {
                const float hv = fmaxf(acc[i][j][r] + bias, 0.0f);
#pragma unroll
                for (int e = 0; e < EE; ++e) part[e] = fmaf(hv, w2r[e], part[e]);
            }
    }

#pragma unroll
    for (int off = 32; off >= 1; off >>= 1)
#pragma unroll
        for (int e = 0; e < EE; ++e) part[e] += __shfl_down(part[e], off, 64);

    if (lane == 0)
#pragma unroll
        for (int e = 0; e < EE; ++e) red[wave][e] = part[e];
    __syncthreads();
    if (tid < EE) {
        const float s = red[0][tid] + red[1][tid] + red[2][tid] + red[3][tid];
        atomicAdd(&chunk_logits[(size_t)bc * EE + tid], s * (1.0f / CHUNK));
    }
}

// ---------------------------------------------------------------------------
// Hysteresis scan: LDS-preload all chunk logits, then per-batch serial scan.
// ---------------------------------------------------------------------------
__global__ void hysteresis_kernel(const float* __restrict__ chunk_logits,
                                  const float* __restrict__ b2,
                                  int* __restrict__ eidx_ws,
                                  float* __restrict__ out_idx)
{
    __shared__ float cls[BB * NCHUNK * EE];   // 2048 floats
    const int tid = threadIdx.x;              // 0..63
#pragma unroll
    for (int i = 0; i < 8; ++i)
        ((float4*)cls)[tid + i * 64] = ((const float4*)chunk_logits)[tid + i * 64];
    __syncthreads();

    const int b = tid;
    if (b >= BB) return;
    float b2r[EE];
#pragma unroll
    for (int e = 0; e < EE; ++e) b2r[e] = b2[e];

    const float* cl = cls + b * NCHUNK * EE;
    int prev = 0;
    for (int c = 0; c < NCHUNK; ++c) {
        float v[EE];
        float best = -3.4e38f;
        int ce = 0;
#pragma unroll
        for (int e = 0; e < EE; ++e) {
            const float lv = cl[c * EE + e] + b2r[e];
            v[e] = lv;
            if (lv > best) { best = lv; ce = e; }
        }
        if (c == 0) prev = ce;
        else if (best - v[prev] > TAU) prev = ce;
        eidx_ws[b * NCHUNK + c] = prev;
        out_idx[b * NCHUNK + c] = (float)prev;
    }
}

// ---------------------------------------------------------------------------
// One-hot routing weights: one thread per token, two float4 stores.
// ---------------------------------------------------------------------------
__global__ __launch_bounds__(256) void onehot_kernel(const int* __restrict__ eidx,
                                                     float* __restrict__ out)
{
    const int tok = blockIdx.x * blockDim.x + threadIdx.x;
    if (tok >= BB * SS) return;
    const int b = tok / SS;
    const int s = tok - b * SS;
    const int idx = eidx[b * NCHUNK + (s / CHUNK)];
    float vals[EE];
#pragma unroll
    for (int e = 0; e < EE; ++e) vals[e] = (e == idx) ? 1.0f : 0.0f;
    float4* o = (float4*)(out + (size_t)tok * EE);
    o[0] = make_float4(vals[0], vals[1], vals[2], vals[3]);
    o[1] = make_float4(vals[4], vals[5], vals[6], vals[7]);
}

// ---------------------------------------------------------------------------
extern "C" void kernel_launch(void* const* d_in, const int* in_sizes, int n_in,
                              void* d_out, int out_size, void* d_ws, size_t ws_size,
                              hipStream_t stream)
{
    const float* x  = (const float*)d_in[0];
    const float* W1 = (const float*)d_in[1];
    const float* b1 = (const float*)d_in[2];
    const float* W2 = (const float*)d_in[3];
    const float* b2 = (const float*)d_in[4];
    float* out = (float*)d_out;

    // ws layout: W1hi (4MB) | W1lo (4MB) | chunk_logits (8KB) | eidx (1KB)
    ushort* w1hi         = (ushort*)d_ws;
    ushort* w1lo         = (ushort*)((char*)d_ws + (size_t)4 * 1024 * 1024);
    float*  chunk_logits = (float*)((char*)d_ws + (size_t)8 * 1024 * 1024);
    int*    eidx         = (int*)((char*)d_ws + (size_t)8 * 1024 * 1024 + 8192);

    hipMemsetAsync(chunk_logits, 0, BB * NCHUNK * EE * sizeof(float), stream);

    reorder_w1_kernel<<<1024, 256, 0, stream>>>(W1, w1hi, w1lo);

    dim3 grid(HH / BN, BB * NCHUNK);   // (8, 256)
    router_gemm_kernel<<<grid, 256, 0, stream>>>(x, w1hi, w1lo, b1, W2, chunk_logits);

    hysteresis_kernel<<<1, 64, 0, stream>>>(chunk_logits, b2, eidx,
                                            out + (size_t)BB * SS * EE);

    onehot_kernel<<<(BB * SS + 255) / 256, 256, 0, stream>>>(eidx, out);
}

// Round 4
// 632.789 us; speedup vs baseline: 1.4137x; 1.4137x over previous
//
#include <hip/hip_runtime.h>

typedef unsigned int uint;
typedef unsigned short ushort;

// Problem constants
#define BB 8
#define SS 4096
#define DD 2048
#define HH 1024
#define EE 8
#define CHUNK 128
#define NCHUNK 32
#define TAU 0.7f

// GEMM tile config (round-0 proven geometry)
#define BM 128
#define BN 128
#define BK 32          // k per LDS buffer (4 groups of 8)
#define KITERS (DD / BK)   // 64

typedef short bf16x8 __attribute__((ext_vector_type(8)));    // 8 bf16 = 4 VGPRs
typedef float f32x16 __attribute__((ext_vector_type(16)));   // 32x32 C frag

// bf16 split helpers: hi = truncate-top-16(x); lo = bf16(x - hi)
__device__ inline uint pack_hi(float a, float b) {
    return (__float_as_uint(a) >> 16) | (__float_as_uint(b) & 0xFFFF0000u);
}
__device__ inline float hi_part(float a) {
    return __uint_as_float(__float_as_uint(a) & 0xFFFF0000u);
}
// RTNE f32 pair -> packed bf16x2 (a in low 16, b in high 16)
__device__ inline uint pack_rn(float a, float b) {
    uint ua = __float_as_uint(a), ub = __float_as_uint(b);
    ua += 0x7FFFu + ((ua >> 16) & 1u);
    ub += 0x7FFFu + ((ub >> 16) & 1u);
    return (ua >> 16) | (ub & 0xFFFF0000u);
}

// ---------------------------------------------------------------------------
// Pre-pass: reorder W1 [D][H] fp32 -> W1hi/W1lo bf16 in MFMA-B-staged layout
// [D/8][H][8] (k-group major, 8 consecutive k per 16B). One thread per (kg,n).
// (unchanged from round 0 — W1 keeps the exact hi/lo split)
// ---------------------------------------------------------------------------
__global__ __launch_bounds__(256) void reorder_w1_kernel(
    const float* __restrict__ W1, ushort* __restrict__ w1hi, ushort* __restrict__ w1lo)
{
    const int kg = blockIdx.x >> 2;                       // 0..255
    const int n  = ((blockIdx.x & 3) << 8) + threadIdx.x; // 0..1023
    float v[8];
#pragma unroll
    for (int j = 0; j < 8; ++j) v[j] = W1[(size_t)(kg * 8 + j) * HH + n];
    uint hi[4], lo[4];
#pragma unroll
    for (int p = 0; p < 4; ++p) {
        const float a = v[2 * p], b = v[2 * p + 1];
        hi[p] = pack_hi(a, b);
        lo[p] = pack_hi(a - hi_part(a), b - hi_part(b));
    }
    const size_t off = (size_t)kg * HH + n;               // uint4 index
    ((uint4*)w1hi)[off] = make_uint4(hi[0], hi[1], hi[2], hi[3]);
    ((uint4*)w1lo)[off] = make_uint4(lo[0], lo[1], lo[2], lo[3]);
}

// ---------------------------------------------------------------------------
// Fused router GEMM (round-0 single-buffer skeleton, 2-term split):
// A = single RTNE bf16 of x; B = exact hi/lo pair of W1.
// acc += a*b_lo + a*b_hi  (2 MFMAs per tile-k instead of 3).
// Epilogue: relu + W2 + chunk-sum -> atomicAdd into chunk_logits.
// ---------------------------------------------------------------------------
__global__ __launch_bounds__(256, 2) void router_gemm_kernel(
    const float* __restrict__ x,
    const ushort* __restrict__ w1hi,   // [D/8][H][8] bf16 bits
    const ushort* __restrict__ w1lo,
    const float* __restrict__ b1,
    const float* __restrict__ W2,
    float* __restrict__ chunk_logits)  // [B*NCHUNK][E], pre-zeroed
{
    const int slice = blockIdx.x;      // 0..7  (H slice)
    const int bc    = blockIdx.y;      // 0..255 (batch*NCHUNK + chunk)
    const int n0    = slice * BN;

    const int tid  = threadIdx.x;      // 0..255
    const int wave = tid >> 6;         // 0..3
    const int lane = tid & 63;
    const int lm   = lane & 31;        // row/col within 32-tile
    const int kq   = lane >> 5;        // k-quadrant (0/1)
    const int wm   = (wave & 1) * 64;  // wave m offset
    const int wn   = (wave >> 1) * 64; // wave n offset

    __shared__ __align__(16) ushort As[4][BM][8];     // [kg][m][8k] bf16, 8KB
    __shared__ __align__(16) ushort Bs_hi[4][BN][8];  // [kg][n][8k], 8KB
    __shared__ __align__(16) ushort Bs_lo[4][BN][8];  // 8KB
    __shared__ float  W2s[BN][EE];                    // 4KB
    __shared__ float  b1s[BN];
    __shared__ float  red[4][EE];

    const float* xrow = x + (size_t)bc * CHUNK * DD;

    // Stage W2 slice + b1 slice
    ((float4*)&W2s[0][0])[tid] = ((const float4*)(W2 + (size_t)n0 * EE))[tid];
    if (tid < BN / 4) ((float4*)b1s)[tid] = ((const float4*)(b1 + n0))[tid];

    f32x16 acc[2][2];
#pragma unroll
    for (int i = 0; i < 2; ++i)
#pragma unroll
        for (int j = 0; j < 2; ++j)
#pragma unroll
            for (int r = 0; r < 16; ++r) acc[i][j][r] = 0.0f;

    // A staging coords: thread -> (m, k-half)
    const int am = tid >> 1;          // 0..127
    const int ah = tid & 1;           // 0/1: k0+ah*16 .. +16

    for (int it = 0; it < KITERS; ++it) {
        const int k0 = it * BK;
        __syncthreads();   // protect LDS from previous iteration's readers

        // ---- B tiles: async global->LDS, 16B/lane, zero VALU ----
        {
            const int kgg = (k0 >> 3) + wave;          // this wave's k-group
#pragma unroll
            for (int h = 0; h < 2; ++h) {
                const size_t goff = ((size_t)kgg * HH + n0 + h * 64 + lane) * 8; // ushort idx
                __builtin_amdgcn_global_load_lds(
                    (const __attribute__((address_space(1))) uint*)(w1hi + goff),
                    (__attribute__((address_space(3))) uint*)&Bs_hi[wave][h * 64 + lane][0],
                    16, 0, 0);
                __builtin_amdgcn_global_load_lds(
                    (const __attribute__((address_space(1))) uint*)(w1lo + goff),
                    (__attribute__((address_space(3))) uint*)&Bs_lo[wave][h * 64 + lane][0],
                    16, 0, 0);
            }
        }

        // ---- A tile: load fp32, RTNE to single bf16, write LDS ----
        {
            const float* src = xrow + (size_t)am * DD + k0 + ah * 16;
            float4 v0 = ((const float4*)src)[0];
            float4 v1 = ((const float4*)src)[1];
            float4 v2 = ((const float4*)src)[2];
            float4 v3 = ((const float4*)src)[3];
            const float f[16] = {v0.x, v0.y, v0.z, v0.w, v1.x, v1.y, v1.z, v1.w,
                                 v2.x, v2.y, v2.z, v2.w, v3.x, v3.y, v3.z, v3.w};
            uint pk[8];
#pragma unroll
            for (int p = 0; p < 8; ++p) pk[p] = pack_rn(f[2 * p], f[2 * p + 1]);
            const int kg0 = ah * 2;
            *(uint4*)&As[kg0][am][0]     = make_uint4(pk[0], pk[1], pk[2], pk[3]);
            *(uint4*)&As[kg0 + 1][am][0] = make_uint4(pk[4], pk[5], pk[6], pk[7]);
        }

        __syncthreads();   // drains vmcnt (global_load_lds) + lgkmcnt

        // ---- MFMA: 2 k-steps x 2x2 tiles x 2 split terms ----
#pragma unroll
        for (int s = 0; s < 2; ++s) {
            const int kg = 2 * s + kq;
            bf16x8 a[2], b_h[2], b_l[2];
#pragma unroll
            for (int i = 0; i < 2; ++i)
                a[i] = *(const bf16x8*)&As[kg][wm + i * 32 + lm][0];
#pragma unroll
            for (int j = 0; j < 2; ++j) {
                b_h[j] = *(const bf16x8*)&Bs_hi[kg][wn + j * 32 + lm][0];
                b_l[j] = *(const bf16x8*)&Bs_lo[kg][wn + j * 32 + lm][0];
            }
#pragma unroll
            for (int i = 0; i < 2; ++i)
#pragma unroll
                for (int j = 0; j < 2; ++j) {
                    acc[i][j] = __builtin_amdgcn_mfma_f32_32x32x16_bf16(
                        a[i], b_l[j], acc[i][j], 0, 0, 0);
                    acc[i][j] = __builtin_amdgcn_mfma_f32_32x32x16_bf16(
                        a[i], b_h[j], acc[i][j], 0, 0, 0);
                }
        }
    }

    // ---- Epilogue: relu + second GEMM + chunk partial sum ----
    float part[EE];
#pragma unroll
    for (int e = 0; e < EE; ++e) part[e] = 0.0f;

#pragma unroll
    for (int j = 0; j < 2; ++j) {
        const int hl = wn + j * 32 + lm;       // local h (col of C)
        const float bias = b1s[hl];
        float w2r[EE];
#pragma unroll
        for (int e = 0; e < EE; ++e) w2r[e] = W2s[hl][e];
#pragma unroll
        for (int i = 0; i < 2; ++i)
#pragma unroll
            for (int r = 0; r < 16; ++r) {
                const float hv = fmaxf(acc[i][j][r] + bias, 0.0f);
#pragma unroll
                for (int e = 0; e < EE; ++e) part[e] = fmaf(hv, w2r[e], part[e]);
            }
    }

#pragma unroll
    for (int off = 32; off >= 1; off >>= 1)
#pragma unroll
        for (int e = 0; e < EE; ++e) part[e] += __shfl_down(part[e], off, 64);

    if (lane == 0)
#pragma unroll
        for (int e = 0; e < EE; ++e) red[wave][e] = part[e];
    __syncthreads();
    if (tid < EE) {
        const float s = red[0][tid] + red[1][tid] + red[2][tid] + red[3][tid];
        atomicAdd(&chunk_logits[(size_t)bc * EE + tid], s * (1.0f / CHUNK));
    }
}

// ---------------------------------------------------------------------------
// Hysteresis scan: LDS-preload all chunk logits, then per-batch serial scan.
// ---------------------------------------------------------------------------
__global__ void hysteresis_kernel(const float* __restrict__ chunk_logits,
                                  const float* __restrict__ b2,
                                  int* __restrict__ eidx_ws,
                                  float* __restrict__ out_idx)
{
    __shared__ float cls[BB * NCHUNK * EE];   // 2048 floats
    const int tid = threadIdx.x;              // 0..63
#pragma unroll
    for (int i = 0; i < 8; ++i)
        ((float4*)cls)[tid + i * 64] = ((const float4*)chunk_logits)[tid + i * 64];
    __syncthreads();

    const int b = tid;
    if (b >= BB) return;
    float b2r[EE];
#pragma unroll
    for (int e = 0; e < EE; ++e) b2r[e] = b2[e];

    const float* cl = cls + b * NCHUNK * EE;
    int prev = 0;
    for (int c = 0; c < NCHUNK; ++c) {
        float v[EE];
        float best = -3.4e38f;
        int ce = 0;
#pragma unroll
        for (int e = 0; e < EE; ++e) {
            const float lv = cl[c * EE + e] + b2r[e];
            v[e] = lv;
            if (lv > best) { best = lv; ce = e; }
        }
        if (c == 0) prev = ce;
        else if (best - v[prev] > TAU) prev = ce;
        eidx_ws[b * NCHUNK + c] = prev;
        out_idx[b * NCHUNK + c] = (float)prev;
    }
}

// ---------------------------------------------------------------------------
// One-hot routing weights: one thread per token, two float4 stores.
// ---------------------------------------------------------------------------
__global__ __launch_bounds__(256) void onehot_kernel(const int* __restrict__ eidx,
                                                     float* __restrict__ out)
{
    const int tok = blockIdx.x * blockDim.x + threadIdx.x;
    if (tok >= BB * SS) return;
    const int b = tok / SS;
    const int s = tok - b * SS;
    const int idx = eidx[b * NCHUNK + (s / CHUNK)];
    float vals[EE];
#pragma unroll
    for (int e = 0; e < EE; ++e) vals[e] = (e == idx) ? 1.0f : 0.0f;
    float4* o = (float4*)(out + (size_t)tok * EE);
    o[0] = make_float4(vals[0], vals[1], vals[2], vals[3]);
    o[1] = make_float4(vals[4], vals[5], vals[6], vals[7]);
}

// ---------------------------------------------------------------------------
extern "C" void kernel_launch(void* const* d_in, const int* in_sizes, int n_in,
                              void* d_out, int out_size, void* d_ws, size_t ws_size,
                              hipStream_t stream)
{
    const float* x  = (const float*)d_in[0];
    const float* W1 = (const float*)d_in[1];
    const float* b1 = (const float*)d_in[2];
    const float* W2 = (const float*)d_in[3];
    const float* b2 = (const float*)d_in[4];
    float* out = (float*)d_out;

    // ws layout: W1hi (4MB) | W1lo (4MB) | chunk_logits (8KB) | eidx (1KB)
    ushort* w1hi         = (ushort*)d_ws;
    ushort* w1lo         = (ushort*)((char*)d_ws + (size_t)4 * 1024 * 1024);
    float*  chunk_logits = (float*)((char*)d_ws + (size_t)8 * 1024 * 1024);
    int*    eidx         = (int*)((char*)d_ws + (size_t)8 * 1024 * 1024 + 8192);

    hipMemsetAsync(chunk_logits, 0, BB * NCHUNK * EE * sizeof(float), stream);

    reorder_w1_kernel<<<1024, 256, 0, stream>>>(W1, w1hi, w1lo);

    dim3 grid(HH / BN, BB * NCHUNK);   // (8, 256)
    router_gemm_kernel<<<grid, 256, 0, stream>>>(x, w1hi, w1lo, b1, W2, chunk_logits);

    hysteresis_kernel<<<1, 64, 0, stream>>>(chunk_logits, b2, eidx,
                                            out + (size_t)BB * SS * EE);

    onehot_kernel<<<(BB * SS + 255) / 256, 256, 0, stream>>>(eidx, out);
}

// Round 5
// 597.174 us; speedup vs baseline: 1.4980x; 1.0596x over previous
//
#include <hip/hip_runtime.h>

typedef unsigned int uint;
typedef unsigned short ushort;

// Problem constants
#define BB 8
#define SS 4096
#define DD 2048
#define HH 1024
#define EE 8
#define CHUNK 128
#define NCHUNK 32
#define TAU 0.7f

// GEMM tile config
#define BM 128
#define BN 256
#define BK 32          // k per LDS buffer (4 groups of 8)
#define KITERS (DD / BK)   // 64
#define NSLICE (HH / BN)   // 4

typedef short bf16x8 __attribute__((ext_vector_type(8)));    // 8 bf16 = 4 VGPRs
typedef float f32x16 __attribute__((ext_vector_type(16)));   // 32x32 C frag

// bf16 split helpers: hi = truncate-top-16(x); lo = bf16(x - hi)
__device__ inline uint pack_hi(float a, float b) {
    return (__float_as_uint(a) >> 16) | (__float_as_uint(b) & 0xFFFF0000u);
}
__device__ inline float hi_part(float a) {
    return __uint_as_float(__float_as_uint(a) & 0xFFFF0000u);
}
// RTNE f32 pair -> packed bf16x2 (a in low 16, b in high 16)
__device__ inline uint pack_rn(float a, float b) {
    uint ua = __float_as_uint(a), ub = __float_as_uint(b);
    ua += 0x7FFFu + ((ua >> 16) & 1u);
    ub += 0x7FFFu + ((ub >> 16) & 1u);
    return (ua >> 16) | (ub & 0xFFFF0000u);
}

// ---------------------------------------------------------------------------
// Pre-pass: reorder W1 [D][H] fp32 -> W1hi/W1lo bf16 in MFMA-B-staged layout
// [D/8][H][8] (k-group major, 8 consecutive k per 16B). One thread per (kg,n).
// ---------------------------------------------------------------------------
__global__ __launch_bounds__(256) void reorder_w1_kernel(
    const float* __restrict__ W1, ushort* __restrict__ w1hi, ushort* __restrict__ w1lo)
{
    const int kg = blockIdx.x >> 2;                       // 0..255
    const int n  = ((blockIdx.x & 3) << 8) + threadIdx.x; // 0..1023
    float v[8];
#pragma unroll
    for (int j = 0; j < 8; ++j) v[j] = W1[(size_t)(kg * 8 + j) * HH + n];
    uint hi[4], lo[4];
#pragma unroll
    for (int p = 0; p < 4; ++p) {
        const float a = v[2 * p], b = v[2 * p + 1];
        hi[p] = pack_hi(a, b);
        lo[p] = pack_hi(a - hi_part(a), b - hi_part(b));
    }
    const size_t off = (size_t)kg * HH + n;               // uint4 index
    ((uint4*)w1hi)[off] = make_uint4(hi[0], hi[1], hi[2], hi[3]);
    ((uint4*)w1lo)[off] = make_uint4(lo[0], lo[1], lo[2], lo[3]);
}

// ---------------------------------------------------------------------------
// Fused router GEMM (single-buffer, 2-term split, BN=256, waves 1x4):
// one block = one (batch,chunk) x one 256-wide H slice. Wave tile 128m x 64n
// (acc[4][2] of 32x32 frags). A = RTNE bf16 of x (packed in-kernel);
// B = exact hi/lo pair of W1 via global_load_lds.
// Epilogue: relu + W2 + chunk-sum -> atomicAdd into chunk_logits.
// ---------------------------------------------------------------------------
__global__ __launch_bounds__(256, 2) void router_gemm_kernel(
    const float* __restrict__ x,
    const ushort* __restrict__ w1hi,   // [D/8][H][8] bf16 bits
    const ushort* __restrict__ w1lo,
    const float* __restrict__ b1,
    const float* __restrict__ W2,
    float* __restrict__ chunk_logits)  // [B*NCHUNK][E], pre-zeroed
{
    const int slice = blockIdx.x;      // 0..3  (H slice)
    const int bc    = blockIdx.y;      // 0..255 (batch*NCHUNK + chunk)
    const int n0    = slice * BN;

    const int tid  = threadIdx.x;      // 0..255
    const int wave = tid >> 6;         // 0..3
    const int lane = tid & 63;
    const int lm   = lane & 31;        // row/col within 32-tile
    const int kq   = lane >> 5;        // k-quadrant (0/1)
    const int wn   = wave * 64;        // wave n offset (1x4 layout, full m)

    __shared__ __align__(16) ushort As[4][BM][8];     // [kg][m][8k] bf16, 8KB
    __shared__ __align__(16) ushort Bs_hi[4][BN][8];  // [kg][n][8k], 16KB
    __shared__ __align__(16) ushort Bs_lo[4][BN][8];  // 16KB
    __shared__ float  W2s[BN][EE];                    // 8KB
    __shared__ float  b1s[BN];                        // 1KB
    __shared__ float  red[4][EE];

    const float* xrow = x + (size_t)bc * CHUNK * DD;

    // Stage W2 slice + b1 slice
    ((float4*)&W2s[0][0])[tid]       = ((const float4*)(W2 + (size_t)n0 * EE))[tid];
    ((float4*)&W2s[0][0])[tid + 256] = ((const float4*)(W2 + (size_t)n0 * EE))[tid + 256];
    if (tid < BN / 4) ((float4*)b1s)[tid] = ((const float4*)(b1 + n0))[tid];

    f32x16 acc[4][2];
#pragma unroll
    for (int i = 0; i < 4; ++i)
#pragma unroll
        for (int j = 0; j < 2; ++j)
#pragma unroll
            for (int r = 0; r < 16; ++r) acc[i][j][r] = 0.0f;

    // A staging coords: thread -> (m, k-half)
    const int am = tid >> 1;          // 0..127
    const int ah = tid & 1;           // 0/1: k0+ah*16 .. +16

    for (int it = 0; it < KITERS; ++it) {
        const int k0 = it * BK;
        __syncthreads();   // protect LDS from previous iteration's readers

        // ---- B tiles: async global->LDS, 16B/lane, zero VALU ----
        {
            const int kgg = (k0 >> 3) + wave;          // this wave's k-group
#pragma unroll
            for (int h = 0; h < 4; ++h) {
                const size_t goff = ((size_t)kgg * HH + n0 + h * 64 + lane) * 8; // ushort idx
                __builtin_amdgcn_global_load_lds(
                    (const __attribute__((address_space(1))) uint*)(w1hi + goff),
                    (__attribute__((address_space(3))) uint*)&Bs_hi[wave][h * 64 + lane][0],
                    16, 0, 0);
                __builtin_amdgcn_global_load_lds(
                    (const __attribute__((address_space(1))) uint*)(w1lo + goff),
                    (__attribute__((address_space(3))) uint*)&Bs_lo[wave][h * 64 + lane][0],
                    16, 0, 0);
            }
        }

        // ---- A tile: load fp32, RTNE to single bf16, write LDS ----
        {
            const float* src = xrow + (size_t)am * DD + k0 + ah * 16;
            float4 v0 = ((const float4*)src)[0];
            float4 v1 = ((const float4*)src)[1];
            float4 v2 = ((const float4*)src)[2];
            float4 v3 = ((const float4*)src)[3];
            const float f[16] = {v0.x, v0.y, v0.z, v0.w, v1.x, v1.y, v1.z, v1.w,
                                 v2.x, v2.y, v2.z, v2.w, v3.x, v3.y, v3.z, v3.w};
            uint pk[8];
#pragma unroll
            for (int p = 0; p < 8; ++p) pk[p] = pack_rn(f[2 * p], f[2 * p + 1]);
            const int kg0 = ah * 2;
            *(uint4*)&As[kg0][am][0]     = make_uint4(pk[0], pk[1], pk[2], pk[3]);
            *(uint4*)&As[kg0 + 1][am][0] = make_uint4(pk[4], pk[5], pk[6], pk[7]);
        }

        __syncthreads();   // drains vmcnt (global_load_lds) + lgkmcnt

        // ---- MFMA: 2 k-steps x 4x2 tiles x 2 split terms ----
#pragma unroll
        for (int s = 0; s < 2; ++s) {
            const int kg = 2 * s + kq;
            bf16x8 a[4], b_h[2], b_l[2];
#pragma unroll
            for (int i = 0; i < 4; ++i)
                a[i] = *(const bf16x8*)&As[kg][i * 32 + lm][0];
#pragma unroll
            for (int j = 0; j < 2; ++j) {
                b_h[j] = *(const bf16x8*)&Bs_hi[kg][wn + j * 32 + lm][0];
                b_l[j] = *(const bf16x8*)&Bs_lo[kg][wn + j * 32 + lm][0];
            }
#pragma unroll
            for (int i = 0; i < 4; ++i)
#pragma unroll
                for (int j = 0; j < 2; ++j) {
                    acc[i][j] = __builtin_amdgcn_mfma_f32_32x32x16_bf16(
                        a[i], b_l[j], acc[i][j], 0, 0, 0);
                    acc[i][j] = __builtin_amdgcn_mfma_f32_32x32x16_bf16(
                        a[i], b_h[j], acc[i][j], 0, 0, 0);
                }
        }
    }

    // ---- Epilogue: relu + second GEMM + chunk partial sum ----
    float part[EE];
#pragma unroll
    for (int e = 0; e < EE; ++e) part[e] = 0.0f;

#pragma unroll
    for (int j = 0; j < 2; ++j) {
        const int hl = wn + j * 32 + lm;       // local h (col of C)
        const float bias = b1s[hl];
        float w2r[EE];
#pragma unroll
        for (int e = 0; e < EE; ++e) w2r[e] = W2s[hl][e];
#pragma unroll
        for (int i = 0; i < 4; ++i)
#pragma unroll
            for (int r = 0; r < 16; ++r) {
                const float hv = fmaxf(acc[i][j][r] + bias, 0.0f);
#pragma unroll
                for (int e = 0; e < EE; ++e) part[e] = fmaf(hv, w2r[e], part[e]);
            }
    }

#pragma unroll
    for (int off = 32; off >= 1; off >>= 1)
#pragma unroll
        for (int e = 0; e < EE; ++e) part[e] += __shfl_down(part[e], off, 64);

    if (lane == 0)
#pragma unroll
        for (int e = 0; e < EE; ++e) red[wave][e] = part[e];
    __syncthreads();
    if (tid < EE) {
        const float s = red[0][tid] + red[1][tid] + red[2][tid] + red[3][tid];
        atomicAdd(&chunk_logits[(size_t)bc * EE + tid], s * (1.0f / CHUNK));
    }
}

// ---------------------------------------------------------------------------
// Hysteresis scan: LDS-preload all chunk logits, then per-batch serial scan.
// ---------------------------------------------------------------------------
__global__ void hysteresis_kernel(const float* __restrict__ chunk_logits,
                                  const float* __restrict__ b2,
                                  int* __restrict__ eidx_ws,
                                  float* __restrict__ out_idx)
{
    __shared__ float cls[BB * NCHUNK * EE];   // 2048 floats
    const int tid = threadIdx.x;              // 0..63
#pragma unroll
    for (int i = 0; i < 8; ++i)
        ((float4*)cls)[tid + i * 64] = ((const float4*)chunk_logits)[tid + i * 64];
    __syncthreads();

    const int b = tid;
    if (b >= BB) return;
    float b2r[EE];
#pragma unroll
    for (int e = 0; e < EE; ++e) b2r[e] = b2[e];

    const float* cl = cls + b * NCHUNK * EE;
    int prev = 0;
    for (int c = 0; c < NCHUNK; ++c) {
        float v[EE];
        float best = -3.4e38f;
        int ce = 0;
#pragma unroll
        for (int e = 0; e < EE; ++e) {
            const float lv = cl[c * EE + e] + b2r[e];
            v[e] = lv;
            if (lv > best) { best = lv; ce = e; }
        }
        if (c == 0) prev = ce;
        else if (best - v[prev] > TAU) prev = ce;
        eidx_ws[b * NCHUNK + c] = prev;
        out_idx[b * NCHUNK + c] = (float)prev;
    }
}

// ---------------------------------------------------------------------------
// One-hot routing weights: one thread per token, two float4 stores.
// ---------------------------------------------------------------------------
__global__ __launch_bounds__(256) void onehot_kernel(const int* __restrict__ eidx,
                                                     float* __restrict__ out)
{
    const int tok = blockIdx.x * blockDim.x + threadIdx.x;
    if (tok >= BB * SS) return;
    const int b = tok / SS;
    const int s = tok - b * SS;
    const int idx = eidx[b * NCHUNK + (s / CHUNK)];
    float vals[EE];
#pragma unroll
    for (int e = 0; e < EE; ++e) vals[e] = (e == idx) ? 1.0f : 0.0f;
    float4* o = (float4*)(out + (size_t)tok * EE);
    o[0] = make_float4(vals[0], vals[1], vals[2], vals[3]);
    o[1] = make_float4(vals[4], vals[5], vals[6], vals[7]);
}

// ---------------------------------------------------------------------------
extern "C" void kernel_launch(void* const* d_in, const int* in_sizes, int n_in,
                              void* d_out, int out_size, void* d_ws, size_t ws_size,
                              hipStream_t stream)
{
    const float* x  = (const float*)d_in[0];
    const float* W1 = (const float*)d_in[1];
    const float* b1 = (const float*)d_in[2];
    const float* W2 = (const float*)d_in[3];
    const float* b2 = (const float*)d_in[4];
    float* out = (float*)d_out;

    // ws layout: W1hi (4MB) | W1lo (4MB) | chunk_logits (8KB) | eidx (1KB)
    ushort* w1hi         = (ushort*)d_ws;
    ushort* w1lo         = (ushort*)((char*)d_ws + (size_t)4 * 1024 * 1024);
    float*  chunk_logits = (float*)((char*)d_ws + (size_t)8 * 1024 * 1024);
    int*    eidx         = (int*)((char*)d_ws + (size_t)8 * 1024 * 1024 + 8192);

    hipMemsetAsync(chunk_logits, 0, BB * NCHUNK * EE * sizeof(float), stream);

    reorder_w1_kernel<<<1024, 256, 0, stream>>>(W1, w1hi, w1lo);

    dim3 grid(NSLICE, BB * NCHUNK);   // (4, 256)
    router_gemm_kernel<<<grid, 256, 0, stream>>>(x, w1hi, w1lo, b1, W2, chunk_logits);

    hysteresis_kernel<<<1, 64, 0, stream>>>(chunk_logits, b2, eidx,
                                            out + (size_t)BB * SS * EE);

    onehot_kernel<<<(BB * SS + 255) / 256, 256, 0, stream>>>(eidx, out);
}

// Round 6
// 569.140 us; speedup vs baseline: 1.5718x; 1.0493x over previous
//
#include <hip/hip_runtime.h>

typedef unsigned int uint;
typedef unsigned short ushort;

// Problem constants
#define BB 8
#define SS 4096
#define DD 2048
#define HH 1024
#define EE 8
#define CHUNK 128
#define NCHUNK 32
#define TAU 0.7f

// GEMM tile config
#define BM 128
#define BN 256
#define BK 32          // k per LDS buffer (4 groups of 8)
#define KITERS (DD / BK)   // 64
#define NSLICE (HH / BN)   // 4

typedef short bf16x8 __attribute__((ext_vector_type(8)));    // 8 bf16 = 4 VGPRs
typedef float f32x16 __attribute__((ext_vector_type(16)));   // 32x32 C frag

// RTNE f32 pair -> packed bf16x2 (a in low 16, b in high 16)
__device__ inline uint pack_rn(float a, float b) {
    uint ua = __float_as_uint(a), ub = __float_as_uint(b);
    ua += 0x7FFFu + ((ua >> 16) & 1u);
    ub += 0x7FFFu + ((ub >> 16) & 1u);
    return (ua >> 16) | (ub & 0xFFFF0000u);
}

// ---------------------------------------------------------------------------
// Pre-pass: reorder W1 [D][H] fp32 -> single RTNE bf16 in MFMA-B-staged layout
// [D/8][H][8] (k-group major, 8 consecutive k per 16B). One thread per (kg,n).
// ---------------------------------------------------------------------------
__global__ __launch_bounds__(256) void reorder_w1_kernel(
    const float* __restrict__ W1, ushort* __restrict__ w1b)
{
    const int kg = blockIdx.x >> 2;                       // 0..255
    const int n  = ((blockIdx.x & 3) << 8) + threadIdx.x; // 0..1023
    float v[8];
#pragma unroll
    for (int j = 0; j < 8; ++j) v[j] = W1[(size_t)(kg * 8 + j) * HH + n];
    uint pk[4];
#pragma unroll
    for (int p = 0; p < 4; ++p) pk[p] = pack_rn(v[2 * p], v[2 * p + 1]);
    const size_t off = (size_t)kg * HH + n;               // uint4 index
    ((uint4*)w1b)[off] = make_uint4(pk[0], pk[1], pk[2], pk[3]);
}

// ---------------------------------------------------------------------------
// Fused router GEMM (single-buffer, single bf16 term, BN=256, waves 1x4):
// one block = one (batch,chunk) x one 256-wide H slice. Wave tile 128m x 64n
// (acc[4][2] of 32x32 frags). A = RTNE bf16 of x (packed in-kernel);
// B = RTNE bf16 of W1 via global_load_lds.
// Epilogue: relu + W2 + chunk-sum -> atomicAdd into chunk_logits.
// ---------------------------------------------------------------------------
__global__ __launch_bounds__(256, 2) void router_gemm_kernel(
    const float* __restrict__ x,
    const ushort* __restrict__ w1b,    // [D/8][H][8] bf16 bits
    const float* __restrict__ b1,
    const float* __restrict__ W2,
    float* __restrict__ chunk_logits)  // [B*NCHUNK][E], pre-zeroed
{
    const int slice = blockIdx.x;      // 0..3  (H slice)
    const int bc    = blockIdx.y;      // 0..255 (batch*NCHUNK + chunk)
    const int n0    = slice * BN;

    const int tid  = threadIdx.x;      // 0..255
    const int wave = tid >> 6;         // 0..3
    const int lane = tid & 63;
    const int lm   = lane & 31;        // row/col within 32-tile
    const int kq   = lane >> 5;        // k-quadrant (0/1)
    const int wn   = wave * 64;        // wave n offset (1x4 layout, full m)

    __shared__ __align__(16) ushort As[4][BM][8];     // [kg][m][8k] bf16, 8KB
    __shared__ __align__(16) ushort Bs[4][BN][8];     // [kg][n][8k], 16KB
    __shared__ float  W2s[BN][EE];                    // 8KB
    __shared__ float  b1s[BN];                        // 1KB
    __shared__ float  red[4][EE];

    const float* xrow = x + (size_t)bc * CHUNK * DD;

    // Stage W2 slice + b1 slice
    ((float4*)&W2s[0][0])[tid]       = ((const float4*)(W2 + (size_t)n0 * EE))[tid];
    ((float4*)&W2s[0][0])[tid + 256] = ((const float4*)(W2 + (size_t)n0 * EE))[tid + 256];
    if (tid < BN / 4) ((float4*)b1s)[tid] = ((const float4*)(b1 + n0))[tid];

    f32x16 acc[4][2];
#pragma unroll
    for (int i = 0; i < 4; ++i)
#pragma unroll
        for (int j = 0; j < 2; ++j)
#pragma unroll
            for (int r = 0; r < 16; ++r) acc[i][j][r] = 0.0f;

    // A staging coords: thread -> (m, k-half)
    const int am = tid >> 1;          // 0..127
    const int ah = tid & 1;           // 0/1: k0+ah*16 .. +16

    for (int it = 0; it < KITERS; ++it) {
        const int k0 = it * BK;
        __syncthreads();   // protect LDS from previous iteration's readers

        // ---- B tile: async global->LDS, 16B/lane, zero VALU ----
        {
            const int kgg = (k0 >> 3) + wave;          // this wave's k-group
#pragma unroll
            for (int h = 0; h < 4; ++h) {
                const size_t goff = ((size_t)kgg * HH + n0 + h * 64 + lane) * 8; // ushort idx
                __builtin_amdgcn_global_load_lds(
                    (const __attribute__((address_space(1))) uint*)(w1b + goff),
                    (__attribute__((address_space(3))) uint*)&Bs[wave][h * 64 + lane][0],
                    16, 0, 0);
            }
        }

        // ---- A tile: load fp32, RTNE to single bf16, write LDS ----
        {
            const float* src = xrow + (size_t)am * DD + k0 + ah * 16;
            float4 v0 = ((const float4*)src)[0];
            float4 v1 = ((const float4*)src)[1];
            float4 v2 = ((const float4*)src)[2];
            float4 v3 = ((const float4*)src)[3];
            const float f[16] = {v0.x, v0.y, v0.z, v0.w, v1.x, v1.y, v1.z, v1.w,
                                 v2.x, v2.y, v2.z, v2.w, v3.x, v3.y, v3.z, v3.w};
            uint pk[8];
#pragma unroll
            for (int p = 0; p < 8; ++p) pk[p] = pack_rn(f[2 * p], f[2 * p + 1]);
            const int kg0 = ah * 2;
            *(uint4*)&As[kg0][am][0]     = make_uint4(pk[0], pk[1], pk[2], pk[3]);
            *(uint4*)&As[kg0 + 1][am][0] = make_uint4(pk[4], pk[5], pk[6], pk[7]);
        }

        __syncthreads();   // drains vmcnt (global_load_lds) + lgkmcnt

        // ---- MFMA: 2 k-steps x 4x2 tiles x 1 term ----
#pragma unroll
        for (int s = 0; s < 2; ++s) {
            const int kg = 2 * s + kq;
            bf16x8 a[4], b[2];
#pragma unroll
            for (int i = 0; i < 4; ++i)
                a[i] = *(const bf16x8*)&As[kg][i * 32 + lm][0];
#pragma unroll
            for (int j = 0; j < 2; ++j)
                b[j] = *(const bf16x8*)&Bs[kg][wn + j * 32 + lm][0];
#pragma unroll
            for (int i = 0; i < 4; ++i)
#pragma unroll
                for (int j = 0; j < 2; ++j)
                    acc[i][j] = __builtin_amdgcn_mfma_f32_32x32x16_bf16(
                        a[i], b[j], acc[i][j], 0, 0, 0);
        }
    }

    // ---- Epilogue: relu + second GEMM + chunk partial sum ----
    float part[EE];
#pragma unroll
    for (int e = 0; e < EE; ++e) part[e] = 0.0f;

#pragma unroll
    for (int j = 0; j < 2; ++j) {
        const int hl = wn + j * 32 + lm;       // local h (col of C)
        const float bias = b1s[hl];
        float w2r[EE];
#pragma unroll
        for (int e = 0; e < EE; ++e) w2r[e] = W2s[hl][e];
#pragma unroll
        for (int i = 0; i < 4; ++i)
#pragma unroll
            for (int r = 0; r < 16; ++r) {
                const float hv = fmaxf(acc[i][j][r] + bias, 0.0f);
#pragma unroll
                for (int e = 0; e < EE; ++e) part[e] = fmaf(hv, w2r[e], part[e]);
            }
    }

#pragma unroll
    for (int off = 32; off >= 1; off >>= 1)
#pragma unroll
        for (int e = 0; e < EE; ++e) part[e] += __shfl_down(part[e], off, 64);

    if (lane == 0)
#pragma unroll
        for (int e = 0; e < EE; ++e) red[wave][e] = part[e];
    __syncthreads();
    if (tid < EE) {
        const float s = red[0][tid] + red[1][tid] + red[2][tid] + red[3][tid];
        atomicAdd(&chunk_logits[(size_t)bc * EE + tid], s * (1.0f / CHUNK));
    }
}

// ---------------------------------------------------------------------------
// Hysteresis scan: LDS-preload all chunk logits, then per-batch serial scan.
// ---------------------------------------------------------------------------
__global__ void hysteresis_kernel(const float* __restrict__ chunk_logits,
                                  const float* __restrict__ b2,
                                  int* __restrict__ eidx_ws,
                                  float* __restrict__ out_idx)
{
    __shared__ float cls[BB * NCHUNK * EE];   // 2048 floats
    const int tid = threadIdx.x;              // 0..63
#pragma unroll
    for (int i = 0; i < 8; ++i)
        ((float4*)cls)[tid + i * 64] = ((const float4*)chunk_logits)[tid + i * 64];
    __syncthreads();

    const int b = tid;
    if (b >= BB) return;
    float b2r[EE];
#pragma unroll
    for (int e = 0; e < EE; ++e) b2r[e] = b2[e];

    const float* cl = cls + b * NCHUNK * EE;
    int prev = 0;
    for (int c = 0; c < NCHUNK; ++c) {
        float v[EE];
        float best = -3.4e38f;
        int ce = 0;
#pragma unroll
        for (int e = 0; e < EE; ++e) {
            const float lv = cl[c * EE + e] + b2r[e];
            v[e] = lv;
            if (lv > best) { best = lv; ce = e; }
        }
        if (c == 0) prev = ce;
        else if (best - v[prev] > TAU) prev = ce;
        eidx_ws[b * NCHUNK + c] = prev;
        out_idx[b * NCHUNK + c] = (float)prev;
    }
}

// ---------------------------------------------------------------------------
// One-hot routing weights: one thread per token, two float4 stores.
// ---------------------------------------------------------------------------
__global__ __launch_bounds__(256) void onehot_kernel(const int* __restrict__ eidx,
                                                     float* __restrict__ out)
{
    const int tok = blockIdx.x * blockDim.x + threadIdx.x;
    if (tok >= BB * SS) return;
    const int b = tok / SS;
    const int s = tok - b * SS;
    const int idx = eidx[b * NCHUNK + (s / CHUNK)];
    float vals[EE];
#pragma unroll
    for (int e = 0; e < EE; ++e) vals[e] = (e == idx) ? 1.0f : 0.0f;
    float4* o = (float4*)(out + (size_t)tok * EE);
    o[0] = make_float4(vals[0], vals[1], vals[2], vals[3]);
    o[1] = make_float4(vals[4], vals[5], vals[6], vals[7]);
}

// ---------------------------------------------------------------------------
extern "C" void kernel_launch(void* const* d_in, const int* in_sizes, int n_in,
                              void* d_out, int out_size, void* d_ws, size_t ws_size,
                              hipStream_t stream)
{
    const float* x  = (const float*)d_in[0];
    const float* W1 = (const float*)d_in[1];
    const float* b1 = (const float*)d_in[2];
    const float* W2 = (const float*)d_in[3];
    const float* b2 = (const float*)d_in[4];
    float* out = (float*)d_out;

    // ws layout: W1b (4MB) | pad | chunk_logits (8KB) | eidx (1KB)
    ushort* w1b          = (ushort*)d_ws;
    float*  chunk_logits = (float*)((char*)d_ws + (size_t)8 * 1024 * 1024);
    int*    eidx         = (int*)((char*)d_ws + (size_t)8 * 1024 * 1024 + 8192);

    hipMemsetAsync(chunk_logits, 0, BB * NCHUNK * EE * sizeof(float), stream);

    reorder_w1_kernel<<<1024, 256, 0, stream>>>(W1, w1b);

    dim3 grid(NSLICE, BB * NCHUNK);   // (4, 256)
    router_gemm_kernel<<<grid, 256, 0, stream>>>(x, w1b, b1, W2, chunk_logits);

    hysteresis_kernel<<<1, 64, 0, stream>>>(chunk_logits, b2, eidx,
                                            out + (size_t)BB * SS * EE);

    onehot_kernel<<<(BB * SS + 255) / 256, 256, 0, stream>>>(eidx, out);
}